// Round 2
// baseline (319.855 us; speedup 1.0000x reference)
//
#include <hip/hip_runtime.h>
#include <hip/hip_bf16.h>
#include <math.h>

#define B_ 2
#define S_ 2048
#define D_ 1024
#define H_ 16
#define HD 64
#define M_ (B_ * S_)     // 4096
#define N_QKV (3 * D_)   // 3072

typedef short short8 __attribute__((ext_vector_type(8)));
typedef float floatx4 __attribute__((ext_vector_type(4)));

// HW RNE f32->bf16 (compiler emits v_cvt_pk_bf16_f32)
static __device__ __forceinline__ unsigned short f2bf(float x) {
    __hip_bfloat16 h = __float2bfloat16(x);
    unsigned short u;
    __builtin_memcpy(&u, &h, sizeof(u));
    return u;
}
static __device__ __forceinline__ float bf2f(unsigned short b) {
    union { unsigned u; float f; } v; v.u = ((unsigned)b) << 16;
    return v.f;
}
// RNE split: x = hi + lo + eps, |eps| ~ 2^-17 |x|
static __device__ __forceinline__ void split2(float x, unsigned short& h, unsigned short& l) {
    h = f2bf(x);
    l = f2bf(x - bf2f(h));
}

// async global->LDS DMA, 16 B per lane (dest = wave-uniform base + lane*16)
static __device__ __forceinline__ void dma16(const void* g, void* l) {
    __builtin_amdgcn_global_load_lds(
        (const __attribute__((address_space(1))) unsigned int*)g,
        (__attribute__((address_space(3))) unsigned int*)l,
        16, 0, 0);
}

// ---------------------------------------------------------------------------
// prep_wT: W[K=1024][N] fp32 -> WT hi/lo bf16 [N][1024]. (verified)
// ---------------------------------------------------------------------------
__global__ __launch_bounds__(256) void prep_wT(
    const float* __restrict__ W, int N,
    unsigned short* __restrict__ Thi, unsigned short* __restrict__ Tlo)
{
    __shared__ float Ws[64][68];
    const int t  = threadIdx.x;
    const int n0 = blockIdx.x * 64, k0 = blockIdx.y * 64;
    {
        const int kl = t >> 4, nl = (t & 15) * 4;
        const float* src = W + (size_t)(k0 + kl) * N + n0 + nl;
#pragma unroll
        for (int g = 0; g < 4; g++)
            *(float4*)&Ws[kl + g * 16][nl] = *(const float4*)(src + (size_t)g * 16 * N);
    }
    __syncthreads();
    {
        const int nl = t >> 2, ks = (t & 3) * 16;
        short8 h0, h1, l0, l1;
#pragma unroll
        for (int j = 0; j < 8; j++) {
            unsigned short hh, ll;
            split2(Ws[ks + j][nl], hh, ll);
            h0[j] = (short)hh; l0[j] = (short)ll;
        }
#pragma unroll
        for (int j = 0; j < 8; j++) {
            unsigned short hh, ll;
            split2(Ws[ks + 8 + j][nl], hh, ll);
            h1[j] = (short)hh; l1[j] = (short)ll;
        }
        unsigned short* dh = Thi + (size_t)(n0 + nl) * D_ + k0 + ks;
        unsigned short* dl = Tlo + (size_t)(n0 + nl) * D_ + k0 + ks;
        *(short8*)dh = h0; *(short8*)(dh + 8) = h1;
        *(short8*)dl = l0; *(short8*)(dl + 8) = l1;
    }
}

// ---------------------------------------------------------------------------
// QKV GEMM: 128x128 tile, DOUBLE-BUFFERED LDS (A+B), stage-first pipeline,
// ONE barrier per K-step (T3 minimum-2-phase). B hi/lo via global_load_lds;
// A register-converted + ds_write. Epilogue: pre-split Q*(1/8), K, V^T.
// ---------------------------------------------------------------------------
__global__ __launch_bounds__(256) void gemm_qkv(
    const float* __restrict__ A,
    const unsigned short* __restrict__ BThi, const unsigned short* __restrict__ BTlo,
    const float* __restrict__ bias,
    unsigned short* __restrict__ Qhi, unsigned short* __restrict__ Qlo,
    unsigned short* __restrict__ Khi, unsigned short* __restrict__ Klo,
    unsigned short* __restrict__ vThi, unsigned short* __restrict__ vTlo)
{
    __shared__ unsigned short sAh[2][128 * 32], sAl[2][128 * 32];
    __shared__ unsigned short sBh[2][128 * 32], sBl[2][128 * 32];   // 64 KB total

    const int t    = threadIdx.x;
    const int m0   = blockIdx.y * 128, n0 = blockIdx.x * 128;
    const int lane = t & 63, wave = t >> 6;
    const int lm   = lane & 15, quad = lane >> 4;
    const int wm   = (wave >> 1) * 64, wn = (wave & 1) * 64;

    const int srow = t >> 1, sseg = (t & 1) * 16;
    const float* Ap = A + (size_t)(m0 + srow) * D_ + sseg;

    const int lrow = lane >> 2, lcol = (lane & 3) * 8;
    const unsigned short* gBh0 = BThi + (size_t)(n0 + wave * 32 + lrow) * D_ + lcol;
    const unsigned short* gBl0 = BTlo + (size_t)(n0 + wave * 32 + lrow) * D_ + lcol;
    const int ldst = wave * 1024 + lane * 8;   // u16 linear dest for DMA

    floatx4 acc[4][4];
#pragma unroll
    for (int i = 0; i < 4; i++)
#pragma unroll
        for (int j = 0; j < 4; j++)
#pragma unroll
            for (int r = 0; r < 4; r++) acc[i][j][r] = 0.f;

    float4 af[4];
    af[0] = *(const float4*)(Ap);     af[1] = *(const float4*)(Ap + 4);
    af[2] = *(const float4*)(Ap + 8); af[3] = *(const float4*)(Ap + 12);

    // convert+write A tile into buf, as a lambda-free macro-ish helper
#define CVT_WRITE_A(BUF)                                                        \
    {                                                                           \
        short8 ah0, ah1, al0, al1;                                              \
        float xs0[8] = {af[0].x, af[0].y, af[0].z, af[0].w,                     \
                        af[1].x, af[1].y, af[1].z, af[1].w};                    \
        float xs1[8] = {af[2].x, af[2].y, af[2].z, af[2].w,                     \
                        af[3].x, af[3].y, af[3].z, af[3].w};                    \
        _Pragma("unroll")                                                       \
        for (int e = 0; e < 8; e++) {                                           \
            unsigned short hh, ll;                                              \
            split2(xs0[e], hh, ll); ah0[e] = (short)hh; al0[e] = (short)ll;     \
            split2(xs1[e], hh, ll); ah1[e] = (short)hh; al1[e] = (short)ll;     \
        }                                                                       \
        unsigned short* a_ = &sAh[BUF][srow * 32 + sseg];                       \
        unsigned short* b_ = &sAl[BUF][srow * 32 + sseg];                       \
        *(short8*)a_ = ah0; *(short8*)(a_ + 8) = ah1;                           \
        *(short8*)b_ = al0; *(short8*)(b_ + 8) = al1;                           \
    }

#define DMA_B(BUF, K0)                                                          \
    {                                                                           \
        dma16(gBh0 + (K0), &sBh[BUF][ldst]);                                    \
        dma16(gBh0 + (size_t)16 * D_ + (K0), &sBh[BUF][ldst + 512]);            \
        dma16(gBl0 + (K0), &sBl[BUF][ldst]);                                    \
        dma16(gBl0 + (size_t)16 * D_ + (K0), &sBl[BUF][ldst + 512]);            \
    }

    // prologue: stage tile 0 into buf 0
    CVT_WRITE_A(0);
    DMA_B(0, 0);
    {
        const float* an = Ap + 32;
        af[0] = *(const float4*)(an);     af[1] = *(const float4*)(an + 4);
        af[2] = *(const float4*)(an + 8); af[3] = *(const float4*)(an + 12);
    }
    __syncthreads();

    int cur = 0;
    for (int k0 = 0; k0 < D_; k0 += 32) {
        // stage NEXT tile into buf^1 (issue before compute: latency hidden)
        if (k0 + 32 < D_) {
            DMA_B(cur ^ 1, k0 + 32);
            CVT_WRITE_A(cur ^ 1);
            if (k0 + 64 < D_) {
                const float* an = Ap + k0 + 64;
                af[0] = *(const float4*)(an);     af[1] = *(const float4*)(an + 4);
                af[2] = *(const float4*)(an + 8); af[3] = *(const float4*)(an + 12);
            }
        }

        short8 bhf[4], blf[4];
#pragma unroll
        for (int nb = 0; nb < 4; nb++) {
            const int r = wn + nb * 16 + lm;
            bhf[nb] = *(const short8*)&sBh[cur][r * 32 + quad * 8];
            blf[nb] = *(const short8*)&sBl[cur][r * 32 + quad * 8];
        }
#pragma unroll
        for (int mb = 0; mb < 4; mb++) {
            const int r = wm + mb * 16 + lm;
            short8 ah = *(const short8*)&sAh[cur][r * 32 + quad * 8];
            short8 al = *(const short8*)&sAl[cur][r * 32 + quad * 8];
#pragma unroll
            for (int nb = 0; nb < 4; nb++) {
                acc[mb][nb] = __builtin_amdgcn_mfma_f32_16x16x32_bf16(ah, bhf[nb], acc[mb][nb], 0, 0, 0);
                acc[mb][nb] = __builtin_amdgcn_mfma_f32_16x16x32_bf16(al, bhf[nb], acc[mb][nb], 0, 0, 0);
                acc[mb][nb] = __builtin_amdgcn_mfma_f32_16x16x32_bf16(ah, blf[nb], acc[mb][nb], 0, 0, 0);
            }
        }
        __syncthreads();   // drains DMA (vmcnt) + LDS reads; one barrier/iter
        cur ^= 1;
    }
#undef CVT_WRITE_A
#undef DMA_B

    const int nmode = n0 >> 10;
    if (nmode == 0) {
#pragma unroll
        for (int nb = 0; nb < 4; nb++) {
            const int c = n0 + wn + nb * 16 + lm;
            const float bv = bias[c];
#pragma unroll
            for (int mb = 0; mb < 4; mb++) {
                const int rowb = m0 + wm + mb * 16 + quad * 4;
#pragma unroll
                for (int r = 0; r < 4; r++) {
                    unsigned short hh, ll;
                    split2((acc[mb][nb][r] + bv) * 0.125f, hh, ll);
                    Qhi[(size_t)(rowb + r) * D_ + c] = hh;
                    Qlo[(size_t)(rowb + r) * D_ + c] = ll;
                }
            }
        }
    } else if (nmode == 1) {
#pragma unroll
        for (int nb = 0; nb < 4; nb++) {
            const int c = n0 + wn + nb * 16 + lm;
            const float bv = bias[c];
            const int cq = c - 1024;
#pragma unroll
            for (int mb = 0; mb < 4; mb++) {
                const int rowb = m0 + wm + mb * 16 + quad * 4;
#pragma unroll
                for (int r = 0; r < 4; r++) {
                    unsigned short hh, ll;
                    split2(acc[mb][nb][r] + bv, hh, ll);
                    Khi[(size_t)(rowb + r) * D_ + cq] = hh;
                    Klo[(size_t)(rowb + r) * D_ + cq] = ll;
                }
            }
        }
    } else {
#pragma unroll
        for (int nb = 0; nb < 4; nb++) {
            const int c = n0 + wn + nb * 16 + lm;
            const float bv = bias[c];
            const int cq = c - 2048;
            const int hh_ = cq >> 6, dd = cq & 63;
#pragma unroll
            for (int mb = 0; mb < 4; mb++) {
                const int rowb = m0 + wm + mb * 16 + quad * 4;
                const int bb = rowb >> 11, ss = rowb & 2047;
                unsigned short hv[4], lv[4];
#pragma unroll
                for (int r = 0; r < 4; r++)
                    split2(acc[mb][nb][r] + bv, hv[r], lv[r]);
                const size_t idx = ((size_t)((bb * 16 + hh_) * 64 + dd)) * S_ + ss;
                *(uint2*)&vThi[idx] = make_uint2((unsigned)hv[0] | ((unsigned)hv[1] << 16),
                                                 (unsigned)hv[2] | ((unsigned)hv[3] << 16));
                *(uint2*)&vTlo[idx] = make_uint2((unsigned)lv[0] | ((unsigned)lv[1] << 16),
                                                 (unsigned)lv[2] | ((unsigned)lv[3] << 16));
            }
        }
    }
}

// ---------------------------------------------------------------------------
// Proj GEMM: 128x64 tiles, 512 blocks (2/CU), fully-DMA DOUBLE-BUFFERED
// pipeline, one barrier/K-step, XCD-chunk swizzle (512%8==0, bijective).
// ---------------------------------------------------------------------------
__global__ __launch_bounds__(256) void gemm_out(
    const unsigned short* __restrict__ Ahi, const unsigned short* __restrict__ Alo,
    const unsigned short* __restrict__ BThi, const unsigned short* __restrict__ BTlo,
    const float* __restrict__ bias, float* __restrict__ C)
{
    __shared__ unsigned short sAh[2][128 * 32], sAl[2][128 * 32];
    __shared__ unsigned short sBh[2][64 * 32],  sBl[2][64 * 32];   // 48 KB

    const int t   = threadIdx.x;
    const int lid = blockIdx.x;                       // 0..511
    const int swz = (lid & 7) * 64 + (lid >> 3);      // XCD-chunk, bijective
    const int bx  = swz & 15, by = swz >> 4;
    const int m0  = by * 128, n0 = bx * 64;
    const int lane = t & 63, wave = t >> 6;
    const int lm   = lane & 15, quad = lane >> 4;
    const int wm   = (wave >> 1) * 64, wn = (wave & 1) * 32;

    const int lrow = lane >> 2, lcol = (lane & 3) * 8;
    const unsigned short* gAh = Ahi + (size_t)(m0 + wave * 32 + lrow) * D_ + lcol;
    const unsigned short* gAl = Alo + (size_t)(m0 + wave * 32 + lrow) * D_ + lcol;
    const unsigned short* gBh = BThi + (size_t)(n0 + (t >> 2)) * D_ + (t & 3) * 8;
    const unsigned short* gBl = BTlo + (size_t)(n0 + (t >> 2)) * D_ + (t & 3) * 8;
    const int adst = wave * 1024 + lane * 8;
    const int bdst = t * 8;

#define STAGE_OUT(BUF, K0)                                                      \
    {                                                                           \
        dma16(gAh + (K0), &sAh[BUF][adst]);                                     \
        dma16(gAh + (size_t)16 * D_ + (K0), &sAh[BUF][adst + 512]);             \
        dma16(gAl + (K0), &sAl[BUF][adst]);                                     \
        dma16(gAl + (size_t)16 * D_ + (K0), &sAl[BUF][adst + 512]);             \
        dma16(gBh + (K0), &sBh[BUF][bdst]);                                     \
        dma16(gBl + (K0), &sBl[BUF][bdst]);                                     \
    }

    floatx4 acc[4][2];
#pragma unroll
    for (int i = 0; i < 4; i++)
#pragma unroll
        for (int j = 0; j < 2; j++)
#pragma unroll
            for (int r = 0; r < 4; r++) acc[i][j][r] = 0.f;

    STAGE_OUT(0, 0);
    __syncthreads();

    int cur = 0;
    for (int k0 = 0; k0 < D_; k0 += 32) {
        if (k0 + 32 < D_) STAGE_OUT(cur ^ 1, k0 + 32);

        short8 bhf[2], blf[2];
#pragma unroll
        for (int nb = 0; nb < 2; nb++) {
            const int r = wn + nb * 16 + lm;
            bhf[nb] = *(const short8*)&sBh[cur][r * 32 + quad * 8];
            blf[nb] = *(const short8*)&sBl[cur][r * 32 + quad * 8];
        }
#pragma unroll
        for (int mb = 0; mb < 4; mb++) {
            const int r = wm + mb * 16 + lm;
            short8 ah = *(const short8*)&sAh[cur][r * 32 + quad * 8];
            short8 al = *(const short8*)&sAl[cur][r * 32 + quad * 8];
#pragma unroll
            for (int nb = 0; nb < 2; nb++) {
                acc[mb][nb] = __builtin_amdgcn_mfma_f32_16x16x32_bf16(ah, bhf[nb], acc[mb][nb], 0, 0, 0);
                acc[mb][nb] = __builtin_amdgcn_mfma_f32_16x16x32_bf16(al, bhf[nb], acc[mb][nb], 0, 0, 0);
                acc[mb][nb] = __builtin_amdgcn_mfma_f32_16x16x32_bf16(ah, blf[nb], acc[mb][nb], 0, 0, 0);
            }
        }
        __syncthreads();
        cur ^= 1;
    }
#undef STAGE_OUT

#pragma unroll
    for (int nb = 0; nb < 2; nb++) {
        const int col = n0 + wn + nb * 16 + lm;
        const float bv = bias[col];
#pragma unroll
        for (int mb = 0; mb < 4; mb++) {
            const int rowb = m0 + wm + mb * 16 + quad * 4;
#pragma unroll
            for (int r = 0; r < 4; r++)
                C[(size_t)(rowb + r) * D_ + col] = acc[mb][nb][r] + bv;
        }
    }
}

// ---------------------------------------------------------------------------
// MFMA flash attention, 128-row Q super-tile / 512 threads (8 waves).
// NEW: K/V double-buffered in LDS -> ONE barrier per k-tile (was 2);
// s_setprio(1) around MFMA clusters (T5). P round-trip is same-wave (rows
// 16w..16w+15 written+read by wave w only) so it needs no barrier.
// ---------------------------------------------------------------------------
#define PST 72   // u16 row stride (64 data + 8 pad)

__global__ __launch_bounds__(512, 2) void flash_attn_mfma(
    unsigned short* QAhi, unsigned short* QAlo,   // Q in, attn out (aliased)
    const unsigned short* __restrict__ Khi, const unsigned short* __restrict__ Klo,
    const unsigned short* __restrict__ vThi, const unsigned short* __restrict__ vTlo)
{
    __shared__ unsigned short KhS[2][64 * PST];
    __shared__ unsigned short KlS[2][64 * PST];
    __shared__ unsigned short VhS[2][64 * PST];   // V^T tile [d][s]
    __shared__ unsigned short VlS[2][64 * PST];
    __shared__ unsigned short PhS[128 * PST];
    __shared__ unsigned short PlS[128 * PST];     // total 108 KB

    const int t    = threadIdx.x;
    const int pj   = blockIdx.x;            // 0..7
    const int bh   = blockIdx.y;
    const int b    = bh >> 4, h = bh & 15;
    const int lane = t & 63, w = t >> 6;    // 8 waves
    const int lm   = lane & 15, quad = lane >> 4;

    const int srow = t >> 3;                // 0..63
    const int sseg = (t & 7) * 8;           // u16 col 0..56

    const unsigned short* Kh_b = Khi + (size_t)(b * S_) * D_ + h * HD + sseg;
    const unsigned short* Kl_b = Klo + (size_t)(b * S_) * D_ + h * HD + sseg;
    const unsigned short* Vh_b = vThi + ((size_t)((b * 16 + h) * 64 + srow)) * S_ + sseg;
    const unsigned short* Vl_b = vTlo + ((size_t)((b * 16 + h) * 64 + srow)) * S_ + sseg;

    const int sdst = srow * PST + sseg;     // LDS staging slot (u16)

    for (int phse = 0; phse < 2; phse++) {
        const int qt = phse ? (15 - pj) : pj;
        const int q0 = qt * 128;
        const int ntiles = 2 * qt + 2;
        const int wdiag = (q0 >> 6) + (w >> 2);   // wave's diagonal k-tile

        // Q fragments (A-layout rows q0+16w+lm), pre-scaled by 1/8
        short8 qh[2], ql[2];
        {
            const size_t qoff = (size_t)(b * S_ + q0 + 16 * w + lm) * D_ + h * HD + quad * 8;
            qh[0] = *(const short8*)&QAhi[qoff];
            qh[1] = *(const short8*)&QAhi[qoff + 32];
            ql[0] = *(const short8*)&QAlo[qoff];
            ql[1] = *(const short8*)&QAlo[qoff + 32];
        }

        float lsum[4] = {0.f, 0.f, 0.f, 0.f};
        floatx4 o[4];
#pragma unroll
        for (int nb = 0; nb < 4; nb++)
#pragma unroll
            for (int r = 0; r < 4; r++) o[nb][r] = 0.f;

        // ---- prologue: stage tile 0 into buf 0, prefetch tile 1 regs
        uint4 pkh, pkl, pvh, pvl;
        pkh = *(const uint4*)(Kh_b + (size_t)srow * D_);
        pkl = *(const uint4*)(Kl_b + (size_t)srow * D_);
        pvh = *(const uint4*)(Vh_b);
        pvl = *(const uint4*)(Vl_b);
        *(uint4*)&KhS[0][sdst] = pkh;
        *(uint4*)&KlS[0][sdst] = pkl;
        *(uint4*)&VhS[0][sdst] = pvh;
        *(uint4*)&VlS[0][sdst] = pvl;
        if (ntiles > 1) {
            pkh = *(const uint4*)(Kh_b + (size_t)(64 + srow) * D_);
            pkl = *(const uint4*)(Kl_b + (size_t)(64 + srow) * D_);
            pvh = *(const uint4*)(Vh_b + 64);
            pvl = *(const uint4*)(Vl_b + 64);
        }
        __syncthreads();

        int cur = 0;
        for (int kt = 0; kt < ntiles; kt++) {
            // write next tile into buf^1 (its reads drained at prev barrier)
            if (kt + 1 < ntiles) {
                *(uint4*)&KhS[cur ^ 1][sdst] = pkh;
                *(uint4*)&KlS[cur ^ 1][sdst] = pkl;
                *(uint4*)&VhS[cur ^ 1][sdst] = pvh;
                *(uint4*)&VlS[cur ^ 1][sdst] = pvl;
            }
            // issue global loads for tile kt+2 (hidden under compute)
            if (kt + 2 < ntiles) {
                const int k1 = (kt + 2) * 64;
                pkh = *(const uint4*)(Kh_b + (size_t)(k1 + srow) * D_);
                pkl = *(const uint4*)(Kl_b + (size_t)(k1 + srow) * D_);
                pvh = *(const uint4*)(Vh_b + k1);
                pvl = *(const uint4*)(Vl_b + k1);
            }

            if (kt <= wdiag) {   // wave-uniform causal skip
                // ---- S = Q K^T (3-MFMA split)
                floatx4 sa[4];
#pragma unroll
                for (int nb = 0; nb < 4; nb++)
#pragma unroll
                    for (int r = 0; r < 4; r++) sa[nb][r] = 0.f;
                __builtin_amdgcn_s_setprio(1);
#pragma unroll
                for (int s = 0; s < 2; s++) {
#pragma unroll
                    for (int nb = 0; nb < 4; nb++) {
                        short8 kh = *(const short8*)&KhS[cur][(nb * 16 + lm) * PST + s * 32 + quad * 8];
                        short8 kl = *(const short8*)&KlS[cur][(nb * 16 + lm) * PST + s * 32 + quad * 8];
                        sa[nb] = __builtin_amdgcn_mfma_f32_16x16x32_bf16(qh[s], kh, sa[nb], 0, 0, 0);
                        sa[nb] = __builtin_amdgcn_mfma_f32_16x16x32_bf16(ql[s], kh, sa[nb], 0, 0, 0);
                        sa[nb] = __builtin_amdgcn_mfma_f32_16x16x32_bf16(qh[s], kl, sa[nb], 0, 0, 0);
                    }
                }
                __builtin_amdgcn_s_setprio(0);

                // ---- softmax-lite (no shift); mask only on the diag tile
                const bool diag = (kt == wdiag);
                const int kbase = kt * 64;
#pragma unroll
                for (int r = 0; r < 4; r++) {
                    const int qabs = q0 + 16 * w + 4 * quad + r;
                    const int rloc = 16 * w + 4 * quad + r;
#pragma unroll
                    for (int nb = 0; nb < 4; nb++) {
                        float p = __expf(sa[nb][r]);
                        if (diag && (kbase + 16 * nb + lm > qabs)) p = 0.f;
                        lsum[r] += p;
                        unsigned short hh, ll;
                        split2(p, hh, ll);
                        PhS[rloc * PST + 16 * nb + lm] = hh;
                        PlS[rloc * PST + 16 * nb + lm] = ll;
                    }
                }

                // ---- O += P V (same-wave P rows; lgkmcnt ordering)
                __builtin_amdgcn_s_setprio(1);
#pragma unroll
                for (int ks = 0; ks < 2; ks++) {
                    short8 pf = *(const short8*)&PhS[(16 * w + lm) * PST + ks * 32 + quad * 8];
                    short8 pg = *(const short8*)&PlS[(16 * w + lm) * PST + ks * 32 + quad * 8];
#pragma unroll
                    for (int nb = 0; nb < 4; nb++) {
                        short8 vhf = *(const short8*)&VhS[cur][(16 * nb + lm) * PST + ks * 32 + quad * 8];
                        short8 vlf = *(const short8*)&VlS[cur][(16 * nb + lm) * PST + ks * 32 + quad * 8];
                        o[nb] = __builtin_amdgcn_mfma_f32_16x16x32_bf16(pf, vhf, o[nb], 0, 0, 0);
                        o[nb] = __builtin_amdgcn_mfma_f32_16x16x32_bf16(pg, vhf, o[nb], 0, 0, 0);
                        o[nb] = __builtin_amdgcn_mfma_f32_16x16x32_bf16(pf, vlf, o[nb], 0, 0, 0);
                    }
                }
                __builtin_amdgcn_s_setprio(0);
            }
            __syncthreads();   // single barrier per tile
            cur ^= 1;
        }

        // epilogue: reduce l, normalize, write attn PRE-SPLIT into Q buffers
#pragma unroll
        for (int r = 0; r < 4; r++) {
            float l = lsum[r];
            l += __shfl_xor(l, 1);
            l += __shfl_xor(l, 2);
            l += __shfl_xor(l, 4);
            l += __shfl_xor(l, 8);
            const float inv = 1.f / l;
            const size_t rowoff =
                (size_t)(b * S_ + q0 + 16 * w + 4 * quad + r) * D_ + h * HD + lm;
#pragma unroll
            for (int nb = 0; nb < 4; nb++) {
                unsigned short hh, ll;
                split2(o[nb][r] * inv, hh, ll);
                QAhi[rowoff + 16 * nb] = hh;
                QAlo[rowoff + 16 * nb] = ll;
            }
        }
    }
}

// ---------------------------------------------------------------------------
extern "C" void kernel_launch(void* const* d_in, const int* in_sizes, int n_in,
                              void* d_out, int out_size, void* d_ws, size_t ws_size,
                              hipStream_t stream)
{
    const float* hs     = (const float*)d_in[0];
    const float* attn_w = (const float*)d_in[1];
    const float* attn_b = (const float*)d_in[2];
    const float* proj_w = (const float*)d_in[3];
    const float* proj_b = (const float*)d_in[4];
    float* outp = (float*)d_out;

    const size_t QE = (size_t)M_ * D_;          // 4,194,304
    const size_t WQ = (size_t)D_ * N_QKV;       // 3,145,728
    unsigned short* Qhi   = (unsigned short*)d_ws;       // also attn hi
    unsigned short* Qlo   = Qhi + QE;                    // also attn lo
    unsigned short* Khi   = Qlo + QE;
    unsigned short* Klo   = Khi + QE;
    unsigned short* vThi  = Klo + QE;
    unsigned short* vTlo  = vThi + QE;
    unsigned short* WqThi = vTlo + QE;
    unsigned short* WqTlo = WqThi + WQ;
    unsigned short* WpThi = WqTlo + WQ;
    unsigned short* WpTlo = WpThi + (size_t)D_ * D_;     // total = 64 MB exactly

    dim3 blk(256);
    prep_wT<<<dim3(N_QKV / 64, D_ / 64), blk, 0, stream>>>(attn_w, N_QKV, WqThi, WqTlo);
    prep_wT<<<dim3(D_ / 64, D_ / 64), blk, 0, stream>>>(proj_w, D_, WpThi, WpTlo);
    gemm_qkv<<<dim3(N_QKV / 128, M_ / 128), blk, 0, stream>>>(
        hs, WqThi, WqTlo, attn_b, Qhi, Qlo, Khi, Klo, vThi, vTlo);
    flash_attn_mfma<<<dim3(8, B_ * H_), dim3(512), 0, stream>>>(
        Qhi, Qlo, Khi, Klo, vThi, vTlo);
    gemm_out<<<dim3(512), blk, 0, stream>>>(
        Qhi, Qlo, WpThi, WpTlo, proj_b, outp);
}

// Round 3
// 316.069 us; speedup vs baseline: 1.0120x; 1.0120x over previous
//
#include <hip/hip_runtime.h>
#include <hip/hip_bf16.h>
#include <math.h>

#define B_ 2
#define S_ 2048
#define D_ 1024
#define H_ 16
#define HD 64
#define M_ (B_ * S_)     // 4096
#define N_QKV (3 * D_)   // 3072

typedef short short8 __attribute__((ext_vector_type(8)));
typedef float floatx4 __attribute__((ext_vector_type(4)));

// HW RNE f32->bf16 (compiler emits v_cvt_pk_bf16_f32)
static __device__ __forceinline__ unsigned short f2bf(float x) {
    __hip_bfloat16 h = __float2bfloat16(x);
    unsigned short u;
    __builtin_memcpy(&u, &h, sizeof(u));
    return u;
}
static __device__ __forceinline__ float bf2f(unsigned short b) {
    union { unsigned u; float f; } v; v.u = ((unsigned)b) << 16;
    return v.f;
}
// RNE split: x = hi + lo + eps, |eps| ~ 2^-17 |x|
static __device__ __forceinline__ void split2(float x, unsigned short& h, unsigned short& l) {
    h = f2bf(x);
    l = f2bf(x - bf2f(h));
}

// async global->LDS DMA, 16 B per lane (dest = wave-uniform base + lane*16)
static __device__ __forceinline__ void dma16(const void* g, void* l) {
    __builtin_amdgcn_global_load_lds(
        (const __attribute__((address_space(1))) unsigned int*)g,
        (__attribute__((address_space(3))) unsigned int*)l,
        16, 0, 0);
}

// ---------------------------------------------------------------------------
// prep_A: hs fp32 [4096][1024] -> Ahi/Alo bf16 (hoists the A split OUT of the
// GEMM K-loop: was re-converted 24x, once per N-column block).
// ---------------------------------------------------------------------------
__global__ __launch_bounds__(256) void prep_A(
    const float* __restrict__ X,
    unsigned short* __restrict__ Ahi, unsigned short* __restrict__ Alo)
{
    const size_t i = ((size_t)blockIdx.x * 256 + threadIdx.x) * 8;
    float4 a = *(const float4*)(X + i);
    float4 b = *(const float4*)(X + i + 4);
    float xs[8] = {a.x, a.y, a.z, a.w, b.x, b.y, b.z, b.w};
    short8 h, l;
#pragma unroll
    for (int e = 0; e < 8; e++) {
        unsigned short hh, ll;
        split2(xs[e], hh, ll);
        h[e] = (short)hh; l[e] = (short)ll;
    }
    *(short8*)&Ahi[i] = h;
    *(short8*)&Alo[i] = l;
}

// ---------------------------------------------------------------------------
// prep_wT: W[K=1024][N] fp32 -> WT hi/lo bf16 [N][1024]. (verified)
// ---------------------------------------------------------------------------
__global__ __launch_bounds__(256) void prep_wT(
    const float* __restrict__ W, int N,
    unsigned short* __restrict__ Thi, unsigned short* __restrict__ Tlo)
{
    __shared__ float Ws[64][68];
    const int t  = threadIdx.x;
    const int n0 = blockIdx.x * 64, k0 = blockIdx.y * 64;
    {
        const int kl = t >> 4, nl = (t & 15) * 4;
        const float* src = W + (size_t)(k0 + kl) * N + n0 + nl;
#pragma unroll
        for (int g = 0; g < 4; g++)
            *(float4*)&Ws[kl + g * 16][nl] = *(const float4*)(src + (size_t)g * 16 * N);
    }
    __syncthreads();
    {
        const int nl = t >> 2, ks = (t & 3) * 16;
        short8 h0, h1, l0, l1;
#pragma unroll
        for (int j = 0; j < 8; j++) {
            unsigned short hh, ll;
            split2(Ws[ks + j][nl], hh, ll);
            h0[j] = (short)hh; l0[j] = (short)ll;
        }
#pragma unroll
        for (int j = 0; j < 8; j++) {
            unsigned short hh, ll;
            split2(Ws[ks + 8 + j][nl], hh, ll);
            h1[j] = (short)hh; l1[j] = (short)ll;
        }
        unsigned short* dh = Thi + (size_t)(n0 + nl) * D_ + k0 + ks;
        unsigned short* dl = Tlo + (size_t)(n0 + nl) * D_ + k0 + ks;
        *(short8*)dh = h0; *(short8*)(dh + 8) = h1;
        *(short8*)dl = l0; *(short8*)(dl + 8) = l1;
    }
}

// ---------------------------------------------------------------------------
// QKV GEMM: m97-verified structure. 128x128 tile, SINGLE 32KB buffer,
// fully-DMA staging (A pre-split by prep_A), ZERO K-loop VALU, 2 barriers
// per K-step (implicit vmcnt(0) drain; inter-block TLP hides latency at
// ~5 blocks/CU). Epilogue: pre-split Q*(1/8), K, V^T.
// ---------------------------------------------------------------------------
__global__ __launch_bounds__(256) void gemm_qkv(
    const unsigned short* __restrict__ Ahi, const unsigned short* __restrict__ Alo,
    const unsigned short* __restrict__ BThi, const unsigned short* __restrict__ BTlo,
    const float* __restrict__ bias,
    unsigned short* __restrict__ Qhi, unsigned short* __restrict__ Qlo,
    unsigned short* __restrict__ Khi, unsigned short* __restrict__ Klo,
    unsigned short* __restrict__ vThi, unsigned short* __restrict__ vTlo)
{
    __shared__ unsigned short sAh[128 * 32], sAl[128 * 32];
    __shared__ unsigned short sBh[128 * 32], sBl[128 * 32];   // 32 KB

    const int t    = threadIdx.x;
    const int m0   = blockIdx.y * 128, n0 = blockIdx.x * 128;
    const int lane = t & 63, wave = t >> 6;
    const int lm   = lane & 15, quad = lane >> 4;
    const int wm   = (wave >> 1) * 64, wn = (wave & 1) * 64;

    const int lrow = lane >> 2, lcol = (lane & 3) * 8;
    const unsigned short* gAh = Ahi + (size_t)(m0 + wave * 32 + lrow) * D_ + lcol;
    const unsigned short* gAl = Alo + (size_t)(m0 + wave * 32 + lrow) * D_ + lcol;
    const unsigned short* gBh = BThi + (size_t)(n0 + wave * 32 + lrow) * D_ + lcol;
    const unsigned short* gBl = BTlo + (size_t)(n0 + wave * 32 + lrow) * D_ + lcol;
    const int ldst = wave * 1024 + lane * 8;   // u16 dest (= base + lane*16B)

    floatx4 acc[4][4];
#pragma unroll
    for (int i = 0; i < 4; i++)
#pragma unroll
        for (int j = 0; j < 4; j++)
#pragma unroll
            for (int r = 0; r < 4; r++) acc[i][j][r] = 0.f;

    for (int k0 = 0; k0 < D_; k0 += 32) {
        __syncthreads();   // readers of previous tile done
        dma16(gAh + k0, &sAh[ldst]);
        dma16(gAh + (size_t)16 * D_ + k0, &sAh[ldst + 512]);
        dma16(gAl + k0, &sAl[ldst]);
        dma16(gAl + (size_t)16 * D_ + k0, &sAl[ldst + 512]);
        dma16(gBh + k0, &sBh[ldst]);
        dma16(gBh + (size_t)16 * D_ + k0, &sBh[ldst + 512]);
        dma16(gBl + k0, &sBl[ldst]);
        dma16(gBl + (size_t)16 * D_ + k0, &sBl[ldst + 512]);
        __syncthreads();   // staged (compiler drains vmcnt(0) here)

        short8 bhf[4], blf[4];
#pragma unroll
        for (int nb = 0; nb < 4; nb++) {
            const int r = wn + nb * 16 + lm;
            bhf[nb] = *(const short8*)&sBh[r * 32 + quad * 8];
            blf[nb] = *(const short8*)&sBl[r * 32 + quad * 8];
        }
#pragma unroll
        for (int mb = 0; mb < 4; mb++) {
            const int r = wm + mb * 16 + lm;
            short8 ah = *(const short8*)&sAh[r * 32 + quad * 8];
            short8 al = *(const short8*)&sAl[r * 32 + quad * 8];
#pragma unroll
            for (int nb = 0; nb < 4; nb++) {
                acc[mb][nb] = __builtin_amdgcn_mfma_f32_16x16x32_bf16(ah, bhf[nb], acc[mb][nb], 0, 0, 0);
                acc[mb][nb] = __builtin_amdgcn_mfma_f32_16x16x32_bf16(al, bhf[nb], acc[mb][nb], 0, 0, 0);
                acc[mb][nb] = __builtin_amdgcn_mfma_f32_16x16x32_bf16(ah, blf[nb], acc[mb][nb], 0, 0, 0);
            }
        }
    }

    const int nmode = n0 >> 10;
    if (nmode == 0) {
#pragma unroll
        for (int nb = 0; nb < 4; nb++) {
            const int c = n0 + wn + nb * 16 + lm;
            const float bv = bias[c];
#pragma unroll
            for (int mb = 0; mb < 4; mb++) {
                const int rowb = m0 + wm + mb * 16 + quad * 4;
#pragma unroll
                for (int r = 0; r < 4; r++) {
                    unsigned short hh, ll;
                    split2((acc[mb][nb][r] + bv) * 0.125f, hh, ll);
                    Qhi[(size_t)(rowb + r) * D_ + c] = hh;
                    Qlo[(size_t)(rowb + r) * D_ + c] = ll;
                }
            }
        }
    } else if (nmode == 1) {
#pragma unroll
        for (int nb = 0; nb < 4; nb++) {
            const int c = n0 + wn + nb * 16 + lm;
            const float bv = bias[c];
            const int cq = c - 1024;
#pragma unroll
            for (int mb = 0; mb < 4; mb++) {
                const int rowb = m0 + wm + mb * 16 + quad * 4;
#pragma unroll
                for (int r = 0; r < 4; r++) {
                    unsigned short hh, ll;
                    split2(acc[mb][nb][r] + bv, hh, ll);
                    Khi[(size_t)(rowb + r) * D_ + cq] = hh;
                    Klo[(size_t)(rowb + r) * D_ + cq] = ll;
                }
            }
        }
    } else {
#pragma unroll
        for (int nb = 0; nb < 4; nb++) {
            const int c = n0 + wn + nb * 16 + lm;
            const float bv = bias[c];
            const int cq = c - 2048;
            const int hh_ = cq >> 6, dd = cq & 63;
#pragma unroll
            for (int mb = 0; mb < 4; mb++) {
                const int rowb = m0 + wm + mb * 16 + quad * 4;
                const int bb = rowb >> 11, ss = rowb & 2047;
                unsigned short hv[4], lv[4];
#pragma unroll
                for (int r = 0; r < 4; r++)
                    split2(acc[mb][nb][r] + bv, hv[r], lv[r]);
                const size_t idx = ((size_t)((bb * 16 + hh_) * 64 + dd)) * S_ + ss;
                *(uint2*)&vThi[idx] = make_uint2((unsigned)hv[0] | ((unsigned)hv[1] << 16),
                                                 (unsigned)hv[2] | ((unsigned)hv[3] << 16));
                *(uint2*)&vTlo[idx] = make_uint2((unsigned)lv[0] | ((unsigned)lv[1] << 16),
                                                 (unsigned)lv[2] | ((unsigned)lv[3] << 16));
            }
        }
    }
}

// ---------------------------------------------------------------------------
// Proj GEMM: 128x64 tiles, 512 blocks (2+/CU), SINGLE 24KB buffer, fully-DMA
// 2-barrier m97 structure, XCD-chunk swizzle (512%8==0, bijective).
// ---------------------------------------------------------------------------
__global__ __launch_bounds__(256) void gemm_out(
    const unsigned short* __restrict__ Ahi, const unsigned short* __restrict__ Alo,
    const unsigned short* __restrict__ BThi, const unsigned short* __restrict__ BTlo,
    const float* __restrict__ bias, float* __restrict__ C)
{
    __shared__ unsigned short sAh[128 * 32], sAl[128 * 32];
    __shared__ unsigned short sBh[64 * 32],  sBl[64 * 32];   // 24 KB

    const int t   = threadIdx.x;
    const int lid = blockIdx.x;                       // 0..511
    const int swz = (lid & 7) * 64 + (lid >> 3);      // XCD-chunk, bijective
    const int bx  = swz & 15, by = swz >> 4;
    const int m0  = by * 128, n0 = bx * 64;
    const int lane = t & 63, wave = t >> 6;
    const int lm   = lane & 15, quad = lane >> 4;
    const int wm   = (wave >> 1) * 64, wn = (wave & 1) * 32;

    const int lrow = lane >> 2, lcol = (lane & 3) * 8;
    const unsigned short* gAh = Ahi + (size_t)(m0 + wave * 32 + lrow) * D_ + lcol;
    const unsigned short* gAl = Alo + (size_t)(m0 + wave * 32 + lrow) * D_ + lcol;
    const unsigned short* gBh = BThi + (size_t)(n0 + (t >> 2)) * D_ + (t & 3) * 8;
    const unsigned short* gBl = BTlo + (size_t)(n0 + (t >> 2)) * D_ + (t & 3) * 8;
    const int adst = wave * 1024 + lane * 8;
    const int bdst = t * 8;

    floatx4 acc[4][2];
#pragma unroll
    for (int i = 0; i < 4; i++)
#pragma unroll
        for (int j = 0; j < 2; j++)
#pragma unroll
            for (int r = 0; r < 4; r++) acc[i][j][r] = 0.f;

    for (int k0 = 0; k0 < D_; k0 += 32) {
        __syncthreads();
        dma16(gAh + k0, &sAh[adst]);
        dma16(gAh + (size_t)16 * D_ + k0, &sAh[adst + 512]);
        dma16(gAl + k0, &sAl[adst]);
        dma16(gAl + (size_t)16 * D_ + k0, &sAl[adst + 512]);
        dma16(gBh + k0, &sBh[bdst]);
        dma16(gBl + k0, &sBl[bdst]);
        __syncthreads();

        short8 bhf[2], blf[2];
#pragma unroll
        for (int nb = 0; nb < 2; nb++) {
            const int r = wn + nb * 16 + lm;
            bhf[nb] = *(const short8*)&sBh[r * 32 + quad * 8];
            blf[nb] = *(const short8*)&sBl[r * 32 + quad * 8];
        }
#pragma unroll
        for (int mb = 0; mb < 4; mb++) {
            const int r = wm + mb * 16 + lm;
            short8 ah = *(const short8*)&sAh[r * 32 + quad * 8];
            short8 al = *(const short8*)&sAl[r * 32 + quad * 8];
#pragma unroll
            for (int nb = 0; nb < 2; nb++) {
                acc[mb][nb] = __builtin_amdgcn_mfma_f32_16x16x32_bf16(ah, bhf[nb], acc[mb][nb], 0, 0, 0);
                acc[mb][nb] = __builtin_amdgcn_mfma_f32_16x16x32_bf16(al, bhf[nb], acc[mb][nb], 0, 0, 0);
                acc[mb][nb] = __builtin_amdgcn_mfma_f32_16x16x32_bf16(ah, blf[nb], acc[mb][nb], 0, 0, 0);
            }
        }
    }

#pragma unroll
    for (int nb = 0; nb < 2; nb++) {
        const int col = n0 + wn + nb * 16 + lm;
        const float bv = bias[col];
#pragma unroll
        for (int mb = 0; mb < 4; mb++) {
            const int rowb = m0 + wm + mb * 16 + quad * 4;
#pragma unroll
            for (int r = 0; r < 4; r++)
                C[(size_t)(rowb + r) * D_ + col] = acc[mb][nb][r] + bv;
        }
    }
}

// ---------------------------------------------------------------------------
// MFMA flash attention (unchanged from R2): 128-row Q super-tile, 8 waves,
// K/V double-buffered, one barrier per k-tile, setprio around MFMA clusters.
// ---------------------------------------------------------------------------
#define PST 72   // u16 row stride (64 data + 8 pad)

__global__ __launch_bounds__(512, 2) void flash_attn_mfma(
    unsigned short* QAhi, unsigned short* QAlo,   // Q in, attn out (aliased)
    const unsigned short* __restrict__ Khi, const unsigned short* __restrict__ Klo,
    const unsigned short* __restrict__ vThi, const unsigned short* __restrict__ vTlo)
{
    __shared__ unsigned short KhS[2][64 * PST];
    __shared__ unsigned short KlS[2][64 * PST];
    __shared__ unsigned short VhS[2][64 * PST];   // V^T tile [d][s]
    __shared__ unsigned short VlS[2][64 * PST];
    __shared__ unsigned short PhS[128 * PST];
    __shared__ unsigned short PlS[128 * PST];     // total 108 KB

    const int t    = threadIdx.x;
    const int pj   = blockIdx.x;            // 0..7
    const int bh   = blockIdx.y;
    const int b    = bh >> 4, h = bh & 15;
    const int lane = t & 63, w = t >> 6;    // 8 waves
    const int lm   = lane & 15, quad = lane >> 4;

    const int srow = t >> 3;                // 0..63
    const int sseg = (t & 7) * 8;           // u16 col 0..56

    const unsigned short* Kh_b = Khi + (size_t)(b * S_) * D_ + h * HD + sseg;
    const unsigned short* Kl_b = Klo + (size_t)(b * S_) * D_ + h * HD + sseg;
    const unsigned short* Vh_b = vThi + ((size_t)((b * 16 + h) * 64 + srow)) * S_ + sseg;
    const unsigned short* Vl_b = vTlo + ((size_t)((b * 16 + h) * 64 + srow)) * S_ + sseg;

    const int sdst = srow * PST + sseg;     // LDS staging slot (u16)

    for (int phse = 0; phse < 2; phse++) {
        const int qt = phse ? (15 - pj) : pj;
        const int q0 = qt * 128;
        const int ntiles = 2 * qt + 2;
        const int wdiag = (q0 >> 6) + (w >> 2);   // wave's diagonal k-tile

        // Q fragments (A-layout rows q0+16w+lm), pre-scaled by 1/8
        short8 qh[2], ql[2];
        {
            const size_t qoff = (size_t)(b * S_ + q0 + 16 * w + lm) * D_ + h * HD + quad * 8;
            qh[0] = *(const short8*)&QAhi[qoff];
            qh[1] = *(const short8*)&QAhi[qoff + 32];
            ql[0] = *(const short8*)&QAlo[qoff];
            ql[1] = *(const short8*)&QAlo[qoff + 32];
        }

        float lsum[4] = {0.f, 0.f, 0.f, 0.f};
        floatx4 o[4];
#pragma unroll
        for (int nb = 0; nb < 4; nb++)
#pragma unroll
            for (int r = 0; r < 4; r++) o[nb][r] = 0.f;

        // ---- prologue: stage tile 0 into buf 0, prefetch tile 1 regs
        uint4 pkh, pkl, pvh, pvl;
        pkh = *(const uint4*)(Kh_b + (size_t)srow * D_);
        pkl = *(const uint4*)(Kl_b + (size_t)srow * D_);
        pvh = *(const uint4*)(Vh_b);
        pvl = *(const uint4*)(Vl_b);
        *(uint4*)&KhS[0][sdst] = pkh;
        *(uint4*)&KlS[0][sdst] = pkl;
        *(uint4*)&VhS[0][sdst] = pvh;
        *(uint4*)&VlS[0][sdst] = pvl;
        if (ntiles > 1) {
            pkh = *(const uint4*)(Kh_b + (size_t)(64 + srow) * D_);
            pkl = *(const uint4*)(Kl_b + (size_t)(64 + srow) * D_);
            pvh = *(const uint4*)(Vh_b + 64);
            pvl = *(const uint4*)(Vl_b + 64);
        }
        __syncthreads();

        int cur = 0;
        for (int kt = 0; kt < ntiles; kt++) {
            // write next tile into buf^1 (its reads drained at prev barrier)
            if (kt + 1 < ntiles) {
                *(uint4*)&KhS[cur ^ 1][sdst] = pkh;
                *(uint4*)&KlS[cur ^ 1][sdst] = pkl;
                *(uint4*)&VhS[cur ^ 1][sdst] = pvh;
                *(uint4*)&VlS[cur ^ 1][sdst] = pvl;
            }
            // issue global loads for tile kt+2 (hidden under compute)
            if (kt + 2 < ntiles) {
                const int k1 = (kt + 2) * 64;
                pkh = *(const uint4*)(Kh_b + (size_t)(k1 + srow) * D_);
                pkl = *(const uint4*)(Kl_b + (size_t)(k1 + srow) * D_);
                pvh = *(const uint4*)(Vh_b + k1);
                pvl = *(const uint4*)(Vl_b + k1);
            }

            if (kt <= wdiag) {   // wave-uniform causal skip
                // ---- S = Q K^T (3-MFMA split)
                floatx4 sa[4];
#pragma unroll
                for (int nb = 0; nb < 4; nb++)
#pragma unroll
                    for (int r = 0; r < 4; r++) sa[nb][r] = 0.f;
                __builtin_amdgcn_s_setprio(1);
#pragma unroll
                for (int s = 0; s < 2; s++) {
#pragma unroll
                    for (int nb = 0; nb < 4; nb++) {
                        short8 kh = *(const short8*)&KhS[cur][(nb * 16 + lm) * PST + s * 32 + quad * 8];
                        short8 kl = *(const short8*)&KlS[cur][(nb * 16 + lm) * PST + s * 32 + quad * 8];
                        sa[nb] = __builtin_amdgcn_mfma_f32_16x16x32_bf16(qh[s], kh, sa[nb], 0, 0, 0);
                        sa[nb] = __builtin_amdgcn_mfma_f32_16x16x32_bf16(ql[s], kh, sa[nb], 0, 0, 0);
                        sa[nb] = __builtin_amdgcn_mfma_f32_16x16x32_bf16(qh[s], kl, sa[nb], 0, 0, 0);
                    }
                }
                __builtin_amdgcn_s_setprio(0);

                // ---- softmax-lite (no shift); mask only on the diag tile
                const bool diag = (kt == wdiag);
                const int kbase = kt * 64;
#pragma unroll
                for (int r = 0; r < 4; r++) {
                    const int qabs = q0 + 16 * w + 4 * quad + r;
                    const int rloc = 16 * w + 4 * quad + r;
#pragma unroll
                    for (int nb = 0; nb < 4; nb++) {
                        float p = __expf(sa[nb][r]);
                        if (diag && (kbase + 16 * nb + lm > qabs)) p = 0.f;
                        lsum[r] += p;
                        unsigned short hh, ll;
                        split2(p, hh, ll);
                        PhS[rloc * PST + 16 * nb + lm] = hh;
                        PlS[rloc * PST + 16 * nb + lm] = ll;
                    }
                }

                // ---- O += P V (same-wave P rows; lgkmcnt ordering)
                __builtin_amdgcn_s_setprio(1);
#pragma unroll
                for (int ks = 0; ks < 2; ks++) {
                    short8 pf = *(const short8*)&PhS[(16 * w + lm) * PST + ks * 32 + quad * 8];
                    short8 pg = *(const short8*)&PlS[(16 * w + lm) * PST + ks * 32 + quad * 8];
#pragma unroll
                    for (int nb = 0; nb < 4; nb++) {
                        short8 vhf = *(const short8*)&VhS[cur][(16 * nb + lm) * PST + ks * 32 + quad * 8];
                        short8 vlf = *(const short8*)&VlS[cur][(16 * nb + lm) * PST + ks * 32 + quad * 8];
                        o[nb] = __builtin_amdgcn_mfma_f32_16x16x32_bf16(pf, vhf, o[nb], 0, 0, 0);
                        o[nb] = __builtin_amdgcn_mfma_f32_16x16x32_bf16(pg, vhf, o[nb], 0, 0, 0);
                        o[nb] = __builtin_amdgcn_mfma_f32_16x16x32_bf16(pf, vlf, o[nb], 0, 0, 0);
                    }
                }
                __builtin_amdgcn_s_setprio(0);
            }
            __syncthreads();   // single barrier per tile
            cur ^= 1;
        }

        // epilogue: reduce l, normalize, write attn PRE-SPLIT into Q buffers
#pragma unroll
        for (int r = 0; r < 4; r++) {
            float l = lsum[r];
            l += __shfl_xor(l, 1);
            l += __shfl_xor(l, 2);
            l += __shfl_xor(l, 4);
            l += __shfl_xor(l, 8);
            const float inv = 1.f / l;
            const size_t rowoff =
                (size_t)(b * S_ + q0 + 16 * w + 4 * quad + r) * D_ + h * HD + lm;
#pragma unroll
            for (int nb = 0; nb < 4; nb++) {
                unsigned short hh, ll;
                split2(o[nb][r] * inv, hh, ll);
                QAhi[rowoff + 16 * nb] = hh;
                QAlo[rowoff + 16 * nb] = ll;
            }
        }
    }
}

// ---------------------------------------------------------------------------
extern "C" void kernel_launch(void* const* d_in, const int* in_sizes, int n_in,
                              void* d_out, int out_size, void* d_ws, size_t ws_size,
                              hipStream_t stream)
{
    const float* hs     = (const float*)d_in[0];
    const float* attn_w = (const float*)d_in[1];
    const float* attn_b = (const float*)d_in[2];
    const float* proj_w = (const float*)d_in[3];
    const float* proj_b = (const float*)d_in[4];
    float* outp = (float*)d_out;

    const size_t QE = (size_t)M_ * D_;          // 4,194,304
    const size_t WQ = (size_t)D_ * N_QKV;       // 3,145,728
    unsigned short* Qhi   = (unsigned short*)d_ws;       // also attn hi
    unsigned short* Qlo   = Qhi + QE;                    // also attn lo
    unsigned short* Khi   = Qlo + QE;
    unsigned short* Klo   = Khi + QE;
    unsigned short* vThi  = Klo + QE;
    unsigned short* vTlo  = vThi + QE;
    unsigned short* WqThi = vTlo + QE;
    unsigned short* WqTlo = WqThi + WQ;
    unsigned short* WpThi = WqTlo + WQ;
    unsigned short* WpTlo = WpThi + (size_t)D_ * D_;
    unsigned short* Ahi   = WpTlo + (size_t)D_ * D_;     // hs pre-split
    unsigned short* Alo   = Ahi + QE;                    // total = 80 MB

    dim3 blk(256);
    prep_A<<<dim3(M_ * D_ / 2048), blk, 0, stream>>>(hs, Ahi, Alo);
    prep_wT<<<dim3(N_QKV / 64, D_ / 64), blk, 0, stream>>>(attn_w, N_QKV, WqThi, WqTlo);
    prep_wT<<<dim3(D_ / 64, D_ / 64), blk, 0, stream>>>(proj_w, D_, WpThi, WpTlo);
    gemm_qkv<<<dim3(N_QKV / 128, M_ / 128), blk, 0, stream>>>(
        Ahi, Alo, WqThi, WqTlo, attn_b, Qhi, Qlo, Khi, Klo, vThi, vTlo);
    flash_attn_mfma<<<dim3(8, B_ * H_), dim3(512), 0, stream>>>(
        Qhi, Qlo, Khi, Klo, vThi, vTlo);
    gemm_out<<<dim3(512), blk, 0, stream>>>(
        Qhi, Qlo, WpThi, WpTlo, proj_b, outp);
}